// Round 9
// baseline (283.374 us; speedup 1.0000x reference)
//
#include <hip/hip_runtime.h>

#define B_ 2
#define S_ 2048
#define E_ 1024
#define H_ 16
#define D_ 64

typedef __bf16 bf16_t;
typedef __bf16 bf16x8 __attribute__((ext_vector_type(8)));
typedef __bf16 bf16x4 __attribute__((ext_vector_type(4)));
typedef float f32x4 __attribute__((ext_vector_type(4)));

// ws layout (bf16 element offsets)
#define OFF_XB   0u           // 3 x [4096][1024] X inputs (inv_s reuses after qkv)
#define OFF_WB   12582912u    // 4 x [1024][1024]  (Wq,Wk,Wv,Wo)
#define OFF_QH   16777216u    // q/k/v heads, 3 x [B,H,S,D]
#define OFF_CTX  29360128u    // [4096][1024]
#define XSZ      4194304u
#define WSZ      1048576u

__device__ __forceinline__ f32x4 mfma16(bf16x8 a, bf16x8 b, f32x4 c) {
  return __builtin_amdgcn_mfma_f32_16x16x32_bf16(a, b, c, 0, 0, 0);
}

__device__ __forceinline__ void gl_lds16(const bf16_t* g, bf16_t* l) {
  __builtin_amdgcn_global_load_lds(
      (const __attribute__((address_space(1))) void*)g,
      (__attribute__((address_space(3))) void*)l, 16, 0, 0);
}

// ---------------------------------------------------------------------------
// Kernel 0: fp32 -> bf16 convert into ws.
// ---------------------------------------------------------------------------
__global__ __launch_bounds__(256) void convert_kernel(
    const float* __restrict__ q, const float* __restrict__ k, const float* __restrict__ v,
    const float* __restrict__ wq, const float* __restrict__ wk,
    const float* __restrict__ wv, const float* __restrict__ wo,
    bf16_t* __restrict__ ws)
{
  const int z = blockIdx.z;
  const float* src;
  bf16_t* dst;
  int n;
  if (z < 3) {
    src = (z == 0) ? q : (z == 1) ? k : v;
    dst = ws + (size_t)z * XSZ;
    n = XSZ;
  } else {
    src = (z == 3) ? wq : (z == 4) ? wk : (z == 5) ? wv : wo;
    dst = ws + OFF_WB + (size_t)(z - 3) * WSZ;
    n = WSZ;
  }
  const int stride = 512 * 256 * 8;
  for (int base = (int)(blockIdx.x * 256 + threadIdx.x) * 8; base < n; base += stride) {
    float4 a = *(const float4*)(src + base);
    float4 b = *(const float4*)(src + base + 4);
    bf16x8 o = { (bf16_t)a.x, (bf16_t)a.y, (bf16_t)a.z, (bf16_t)a.w,
                 (bf16_t)b.x, (bf16_t)b.y, (bf16_t)b.z, (bf16_t)b.w };
    *(bf16x8*)(dst + base) = o;
  }
}

// ---------------------------------------------------------------------------
// Kernel 1: QKV projection, m97 structure.
// ---------------------------------------------------------------------------
__global__ __launch_bounds__(256) void qkv_gemm_kernel(
    bf16_t* __restrict__ wsb,
    const float* __restrict__ bq, const float* __restrict__ bk, const float* __restrict__ bv)
{
  __shared__ __align__(16) bf16_t sA[128 * 64];
  __shared__ __align__(16) bf16_t sB[128 * 64];

  const int z = blockIdx.z;
  const bf16_t* A  = wsb + (size_t)z * XSZ;
  const bf16_t* Bm = wsb + OFF_WB + (size_t)z * WSZ;
  const float* bias = (z == 0) ? bq : (z == 1) ? bk : bv;
  bf16_t* out = wsb + OFF_QH + (size_t)z * XSZ;

  const int t = threadIdx.x, lane = t & 63, w = t >> 6;
  const int wm = (w >> 1) << 6, wn = (w & 1) << 6;
  const int m0 = blockIdx.x << 7, n0 = blockIdx.y << 7;
  const int l15 = lane & 15, lg = lane >> 4;

  const int r0 = w << 5;
  const int grow = r0 + (lane >> 3);
  const int gcol = (lane & 7) << 3;
  const bf16_t* gA = A + ((size_t)(m0 + grow) << 10) + gcol;
  const bf16_t* gB = Bm + ((size_t)(n0 + grow) << 10) + gcol;
  bf16_t* lA = sA + (r0 << 6);
  bf16_t* lB = sB + (r0 << 6);

  f32x4 acc[4][4] = {};

  for (int k0 = 0; k0 < E_; k0 += 64) {
    __syncthreads();
#pragma unroll
    for (int i = 0; i < 4; ++i) {
      gl_lds16(gA + k0 + ((size_t)(i << 3) << 10), lA + (i << 9));
      gl_lds16(gB + k0 + ((size_t)(i << 3) << 10), lB + (i << 9));
    }
    __syncthreads();
#pragma unroll
    for (int kk = 0; kk < 2; ++kk) {
      bf16x8 af[4], bfr[4];
#pragma unroll
      for (int i = 0; i < 4; ++i)
        af[i] = *(const bf16x8*)(sA + ((wm + (i << 4) + l15) << 6) + (kk << 5) + (lg << 3));
#pragma unroll
      for (int j = 0; j < 4; ++j)
        bfr[j] = *(const bf16x8*)(sB + ((wn + (j << 4) + l15) << 6) + (kk << 5) + (lg << 3));
#pragma unroll
      for (int i = 0; i < 4; ++i)
#pragma unroll
        for (int j = 0; j < 4; ++j)
          acc[i][j] = mfma16(af[i], bfr[j], acc[i][j]);
    }
  }

#pragma unroll
  for (int j = 0; j < 4; ++j) {
    const int n = n0 + wn + (j << 4) + l15;
    const float bn = bias[n];
    const int h = n >> 6, d = n & 63;
#pragma unroll
    for (int i = 0; i < 4; ++i) {
#pragma unroll
      for (int r = 0; r < 4; ++r) {
        const int m = m0 + wm + (i << 4) + (lg << 2) + r;
        const int b = m >> 11, s = m & (S_ - 1);
        out[(((size_t)(b * H_ + h)) * S_ + s) * D_ + d] = (bf16_t)(acc[i][j][r] + bn);
      }
    }
  }
}

// ---------------------------------------------------------------------------
// Kernel 2a: attention row sums + chunked zero-fill.  grid (32 qt, 32 bh).
// Sums-only QK^T loop (no V/PV).  The upper-triangle zero tiles (31-qt of
// them) are issued in chunks inside the kt loop so their HBM drain overlaps
// the MFMA compute; work is complementary (fill ~ 31-qt, compute ~ qt+1).
// ---------------------------------------------------------------------------
__global__ __launch_bounds__(256) void attn_sums_kernel(
    const bf16_t* __restrict__ qh, const bf16_t* __restrict__ kh,
    float* __restrict__ inv_s_g, float* __restrict__ attn)
{
  constexpr int STR = 72;
  __shared__ __align__(16) bf16_t klds[64 * STR];

  const int t    = threadIdx.x;
  const int lane = t & 63;
  const int w    = t >> 6;
  const int l15  = lane & 15;
  const int lg   = lane >> 4;
  const int qt = blockIdx.x;
  const int bh = blockIdx.y;
  const int q0 = qt << 6;
  const size_t hbase = (size_t)bh * (size_t)(S_ * D_);

  const int qr_lane = q0 + (w << 4) + l15;
  const bf16_t* qp = qh + hbase + (size_t)qr_lane * D_ + (lg << 3);
  const bf16x8 q_lo = *(const bf16x8*)qp;
  const bf16x8 q_hi = *(const bf16x8*)(qp + 32);

  constexpr float SC = 0.18033688f;  // log2(e)/8
  float s_sum = 0.f;

  const int sr = t >> 3;                // 0..31
  const int sc = (t & 7) << 3;          // 0..56

  // fill bookkeeping
  float* attn_bh = attn + (size_t)bh * (size_t)(S_ * S_);
  const int frow = t >> 4;              // 0..15
  const int fcol = (t & 15) << 2;       // 0..60
  const int nfill = 31 - qt;
  const int iters = qt + 1;
  int fdone = 0;
  const f32x4 fz = { 0.f, 0.f, 0.f, 0.f };

  for (int kt = 0; kt <= qt; ++kt) {
    __syncthreads();
    {
      const bf16_t* kb = kh + hbase + (size_t)((kt << 6) + sr) * D_ + sc;
      *(bf16x8*)(klds + sr * STR + sc) = *(const bf16x8*)kb;
      *(bf16x8*)(klds + (sr + 32) * STR + sc) = *(const bf16x8*)(kb + 32 * D_);
    }
    __syncthreads();
#pragma unroll
    for (int j = 0; j < 4; ++j) {
      const bf16_t* kp = klds + ((j << 4) + l15) * STR + (lg << 3);
      bf16x8 k_lo = *(const bf16x8*)kp;
      bf16x8 k_hi = *(const bf16x8*)(kp + 32);
      f32x4 sf = { 0.f, 0.f, 0.f, 0.f };
      sf = mfma16(k_lo, q_lo, sf);
      sf = mfma16(k_hi, q_hi, sf);
      const int kc = (kt << 6) + (j << 4) + (lg << 2);
      const int lim = qr_lane - kc;
#pragma unroll
      for (int r = 0; r < 4; ++r)
        s_sum += (r <= lim) ? exp2f(sf[r] * SC) : 0.f;
    }
    // chunked zero-fill: issue this iteration's share of upper-tri tiles
    const int ftarget = (nfill * (kt + 1)) / iters;
    for (; fdone < ftarget; ++fdone) {
      const int kcol0 = (qt + 1 + fdone) << 6;
#pragma unroll
      for (int rr = 0; rr < 4; ++rr)
        __builtin_nontemporal_store(fz,
            (f32x4*)(attn_bh + (size_t)(q0 + (rr << 4) + frow) * S_ + kcol0 + fcol));
    }
  }

  float s = s_sum;
  s += __shfl_xor(s, 16);
  s += __shfl_xor(s, 32);
  if (lane < 16)
    inv_s_g[(bh << 11) + qr_lane] = 1.f / s;
}

// ---------------------------------------------------------------------------
// Kernel 2b: P materialization + PV + attn store.  grid (32 qt, 32 bh).
// Per tile: compute normalized P once (swapped QK^T), write bf16 -> plds;
// PV MFMA consumes plds; cooperative full-line stores (bf16->f32 cvt) write
// attn from plds.  Stores drain under the next tile's compute.
// ---------------------------------------------------------------------------
__global__ __launch_bounds__(256) void attn_pv_store_kernel(
    const bf16_t* __restrict__ qh, const bf16_t* __restrict__ kh, const bf16_t* __restrict__ vh,
    const float* __restrict__ inv_s_g, float* __restrict__ attn, bf16_t* __restrict__ ctx)
{
  constexpr int STR = 72;
  __shared__ __align__(16) bf16_t klds[64 * STR];
  __shared__ __align__(16) bf16_t vrm [64 * 64];     // V row-major [k][d]
  __shared__ __align__(16) bf16_t vt  [64 * STR];    // V^T [d][k]
  __shared__ __align__(16) bf16_t plds[4][16 * STR]; // normalized P [qrow][kcol]

  const int t    = threadIdx.x;
  const int lane = t & 63;
  const int w    = t >> 6;
  const int l15  = lane & 15;
  const int lg   = lane >> 4;
  const int qt = blockIdx.x;
  const int bh = blockIdx.y;
  const int q0 = qt << 6;
  const size_t hbase = (size_t)bh * (size_t)(S_ * D_);

  const int qr_lane = q0 + (w << 4) + l15;
  const bf16_t* qp = qh + hbase + (size_t)qr_lane * D_ + (lg << 3);
  const bf16x8 q_lo = *(const bf16x8*)qp;
  const bf16x8 q_hi = *(const bf16x8*)(qp + 32);
  const float inv_s = inv_s_g[(bh << 11) + qr_lane];

  constexpr float SC = 0.18033688f;  // log2(e)/8
  f32x4 oacc[4] = {};

  const int td  = t & 63;
  const int tk0 = (t >> 6) << 3;
  const int sr = t >> 3;
  const int sc = (t & 7) << 3;
  const int frow = t >> 4;
  const int fcol = (t & 15) << 2;

  float* attn_bh = attn + (size_t)bh * (size_t)(S_ * S_);

  for (int kt = 0; kt <= qt; ++kt) {
    __syncthreads();   // prev coop-reads of plds/vt done
    {
      const bf16_t* kb = kh + hbase + (size_t)((kt << 6) + sr) * D_ + sc;
      const bf16_t* vb = vh + hbase + (size_t)((kt << 6) + sr) * D_ + sc;
      *(bf16x8*)(klds + sr * STR + sc) = *(const bf16x8*)kb;
      *(bf16x8*)(klds + (sr + 32) * STR + sc) = *(const bf16x8*)(kb + 32 * D_);
      *(bf16x8*)(vrm + (sr << 6) + sc) = *(const bf16x8*)vb;
      *(bf16x8*)(vrm + ((sr + 32) << 6) + sc) = *(const bf16x8*)(vb + 32 * D_);
    }
    __syncthreads();
    // V transpose: column reads (conflict-free) + b128 row writes
#pragma unroll
    for (int rep = 0; rep < 2; ++rep) {
      const int k0 = tk0 + (rep << 5);
      bf16x8 col;
#pragma unroll
      for (int e = 0; e < 8; ++e) col[e] = vrm[((k0 + e) << 6) + td];
      *(bf16x8*)(vt + td * STR + k0) = col;
    }
    // swapped QK^T -> normalized P -> plds (bf16)
#pragma unroll
    for (int j = 0; j < 4; ++j) {
      const bf16_t* kp = klds + ((j << 4) + l15) * STR + (lg << 3);
      bf16x8 k_lo = *(const bf16x8*)kp;
      bf16x8 k_hi = *(const bf16x8*)(kp + 32);
      f32x4 sf = { 0.f, 0.f, 0.f, 0.f };
      sf = mfma16(k_lo, q_lo, sf);
      sf = mfma16(k_hi, q_hi, sf);
      const int kc = (kt << 6) + (j << 4) + (lg << 2);
      const int lim = qr_lane - kc;
      bf16x4 pb;
#pragma unroll
      for (int r = 0; r < 4; ++r)
        pb[r] = (bf16_t)((r <= lim) ? exp2f(sf[r] * SC) * inv_s : 0.f);
      *(bf16x4*)(&plds[w][l15 * STR + (j << 4) + (lg << 2)]) = pb;
    }
    __syncthreads();   // vt + plds (all waves) ready
    // PV
#pragma unroll
    for (int kk = 0; kk < 2; ++kk) {
      bf16x8 pa = *(const bf16x8*)(&plds[w][l15 * STR + (kk << 5) + (lg << 3)]);
#pragma unroll
      for (int db = 0; db < 4; ++db) {
        bf16x8 vb = *(const bf16x8*)(vt + ((db << 4) + l15) * STR + (kk << 5) + (lg << 3));
        oacc[db] = mfma16(pa, vb, oacc[db]);
      }
    }
    // cooperative full-line store of this tile's P (bf16 -> f32)
#pragma unroll
    for (int rr = 0; rr < 4; ++rr) {
      bf16x4 pv4 = *(const bf16x4*)(&plds[rr][frow * STR + fcol]);
      f32x4 o = { (float)pv4[0], (float)pv4[1], (float)pv4[2], (float)pv4[3] };
      __builtin_nontemporal_store(o,
          (f32x4*)(attn_bh + (size_t)(q0 + (rr << 4) + frow) * S_ + (kt << 6) + fcol));
    }
  }

  // ctx write (P already normalized)
  const int b = bh >> 4, h = bh & 15;
  const int qr_base = q0 + (w << 4) + (lg << 2);
#pragma unroll
  for (int db = 0; db < 4; ++db) {
    const int d = (db << 4) + l15;
#pragma unroll
    for (int r = 0; r < 4; ++r) {
      const int qr = qr_base + r;
      ctx[((size_t)(b * S_ + qr)) * E_ + h * D_ + d] = (bf16_t)oacc[db][r];
    }
  }
}

// ---------------------------------------------------------------------------
// Kernel 3: output projection, m97 structure.
// ---------------------------------------------------------------------------
__global__ __launch_bounds__(256) void out_gemm_kernel(
    bf16_t* __restrict__ wsb, const float* __restrict__ bo, float* __restrict__ out)
{
  __shared__ __align__(16) bf16_t sA[128 * 64];
  __shared__ __align__(16) bf16_t sB[128 * 64];

  const bf16_t* A  = wsb + OFF_CTX;
  const bf16_t* Bm = wsb + OFF_WB + 3u * WSZ;

  const int t = threadIdx.x, lane = t & 63, w = t >> 6;
  const int wm = (w >> 1) << 6, wn = (w & 1) << 6;
  const int m0 = blockIdx.x << 7, n0 = blockIdx.y << 7;
  const int l15 = lane & 15, lg = lane >> 4;

  const int r0 = w << 5;
  const int grow = r0 + (lane >> 3);
  const int gcol = (lane & 7) << 3;
  const bf16_t* gA = A + ((size_t)(m0 + grow) << 10) + gcol;
  const bf16_t* gB = Bm + ((size_t)(n0 + grow) << 10) + gcol;
  bf16_t* lA = sA + (r0 << 6);
  bf16_t* lB = sB + (r0 << 6);

  f32x4 acc[4][4] = {};

  for (int k0 = 0; k0 < E_; k0 += 64) {
    __syncthreads();
#pragma unroll
    for (int i = 0; i < 4; ++i) {
      gl_lds16(gA + k0 + ((size_t)(i << 3) << 10), lA + (i << 9));
      gl_lds16(gB + k0 + ((size_t)(i << 3) << 10), lB + (i << 9));
    }
    __syncthreads();
#pragma unroll
    for (int kk = 0; kk < 2; ++kk) {
      bf16x8 af[4], bfr[4];
#pragma unroll
      for (int i = 0; i < 4; ++i)
        af[i] = *(const bf16x8*)(sA + ((wm + (i << 4) + l15) << 6) + (kk << 5) + (lg << 3));
#pragma unroll
      for (int j = 0; j < 4; ++j)
        bfr[j] = *(const bf16x8*)(sB + ((wn + (j << 4) + l15) << 6) + (kk << 5) + (lg << 3));
#pragma unroll
      for (int i = 0; i < 4; ++i)
#pragma unroll
        for (int j = 0; j < 4; ++j)
          acc[i][j] = mfma16(af[i], bfr[j], acc[i][j]);
    }
  }

#pragma unroll
  for (int j = 0; j < 4; ++j) {
    const int n = n0 + wn + (j << 4) + l15;
    const float bn = bo[n];
#pragma unroll
    for (int i = 0; i < 4; ++i) {
#pragma unroll
      for (int r = 0; r < 4; ++r) {
        const int m = m0 + wm + (i << 4) + (lg << 2) + r;
        out[(size_t)m * E_ + n] = acc[i][j][r] + bn;
      }
    }
  }
}

// ---------------------------------------------------------------------------
extern "C" void kernel_launch(void* const* d_in, const int* in_sizes, int n_in,
                              void* d_out, int out_size, void* d_ws, size_t ws_size,
                              hipStream_t stream) {
  const float* query = (const float*)d_in[0];
  const float* key   = (const float*)d_in[1];
  const float* value = (const float*)d_in[2];
  const float* Wq = (const float*)d_in[4];
  const float* bq = (const float*)d_in[5];
  const float* Wk = (const float*)d_in[6];
  const float* bk = (const float*)d_in[7];
  const float* Wv = (const float*)d_in[8];
  const float* bv = (const float*)d_in[9];
  const float* Wo = (const float*)d_in[10];
  const float* bo = (const float*)d_in[11];

  float* out  = (float*)d_out;                       // [B,S,E]
  float* attn = out + (size_t)B_ * S_ * E_;          // [B,H,S,S]

  bf16_t* wsb = (bf16_t*)d_ws;
  bf16_t* qh  = wsb + OFF_QH;
  bf16_t* kh  = qh + XSZ;
  bf16_t* vh  = kh + XSZ;
  bf16_t* ctx = wsb + OFF_CTX;
  // inv_s reuses the X-input region (dead after qkv_gemm)
  float* inv_s_g = (float*)d_ws;

  convert_kernel<<<dim3(512, 1, 7), dim3(256), 0, stream>>>(
      query, key, value, Wq, Wk, Wv, Wo, wsb);
  qkv_gemm_kernel<<<dim3(32, 8, 3), dim3(256), 0, stream>>>(wsb, bq, bk, bv);
  attn_sums_kernel<<<dim3(32, 32), dim3(256), 0, stream>>>(qh, kh, inv_s_g, attn);
  attn_pv_store_kernel<<<dim3(32, 32), dim3(256), 0, stream>>>(qh, kh, vh, inv_s_g, attn, ctx);
  out_gemm_kernel<<<dim3(32, 8), dim3(256), 0, stream>>>(wsb, bo, out);
}

// Round 10
// 262.002 us; speedup vs baseline: 1.0816x; 1.0816x over previous
//
#include <hip/hip_runtime.h>

#define B_ 2
#define S_ 2048
#define E_ 1024
#define H_ 16
#define D_ 64

typedef __bf16 bf16_t;
typedef __bf16 bf16x8 __attribute__((ext_vector_type(8)));
typedef __bf16 bf16x4 __attribute__((ext_vector_type(4)));
typedef float f32x4 __attribute__((ext_vector_type(4)));

// ws layout (bf16 element offsets)
#define OFF_XB   0u           // 3 x [4096][1024] X inputs
#define OFF_WB   12582912u    // 4 x [1024][1024]  (Wq,Wk,Wv,Wo)
#define OFF_QH   16777216u    // q/k/v heads, 3 x [B,H,S,D]
#define OFF_CTX  29360128u    // [4096][1024]
#define XSZ      4194304u
#define WSZ      1048576u

__device__ __forceinline__ f32x4 mfma16(bf16x8 a, bf16x8 b, f32x4 c) {
  return __builtin_amdgcn_mfma_f32_16x16x32_bf16(a, b, c, 0, 0, 0);
}

__device__ __forceinline__ void gl_lds16(const bf16_t* g, bf16_t* l) {
  __builtin_amdgcn_global_load_lds(
      (const __attribute__((address_space(1))) void*)g,
      (__attribute__((address_space(3))) void*)l, 16, 0, 0);
}

// ---------------------------------------------------------------------------
// Kernel 0: fp32 -> bf16 convert into ws.
// ---------------------------------------------------------------------------
__global__ __launch_bounds__(256) void convert_kernel(
    const float* __restrict__ q, const float* __restrict__ k, const float* __restrict__ v,
    const float* __restrict__ wq, const float* __restrict__ wk,
    const float* __restrict__ wv, const float* __restrict__ wo,
    bf16_t* __restrict__ ws)
{
  const int z = blockIdx.z;
  const float* src;
  bf16_t* dst;
  int n;
  if (z < 3) {
    src = (z == 0) ? q : (z == 1) ? k : v;
    dst = ws + (size_t)z * XSZ;
    n = XSZ;
  } else {
    src = (z == 3) ? wq : (z == 4) ? wk : (z == 5) ? wv : wo;
    dst = ws + OFF_WB + (size_t)(z - 3) * WSZ;
    n = WSZ;
  }
  const int stride = 512 * 256 * 8;
  for (int base = (int)(blockIdx.x * 256 + threadIdx.x) * 8; base < n; base += stride) {
    float4 a = *(const float4*)(src + base);
    float4 b = *(const float4*)(src + base + 4);
    bf16x8 o = { (bf16_t)a.x, (bf16_t)a.y, (bf16_t)a.z, (bf16_t)a.w,
                 (bf16_t)b.x, (bf16_t)b.y, (bf16_t)b.z, (bf16_t)b.w };
    *(bf16x8*)(dst + base) = o;
  }
}

// ---------------------------------------------------------------------------
// Kernel 1: QKV projection, m97 structure.
// ---------------------------------------------------------------------------
__global__ __launch_bounds__(256) void qkv_gemm_kernel(
    bf16_t* __restrict__ wsb,
    const float* __restrict__ bq, const float* __restrict__ bk, const float* __restrict__ bv)
{
  __shared__ __align__(16) bf16_t sA[128 * 64];
  __shared__ __align__(16) bf16_t sB[128 * 64];

  const int z = blockIdx.z;
  const bf16_t* A  = wsb + (size_t)z * XSZ;
  const bf16_t* Bm = wsb + OFF_WB + (size_t)z * WSZ;
  const float* bias = (z == 0) ? bq : (z == 1) ? bk : bv;
  bf16_t* out = wsb + OFF_QH + (size_t)z * XSZ;

  const int t = threadIdx.x, lane = t & 63, w = t >> 6;
  const int wm = (w >> 1) << 6, wn = (w & 1) << 6;
  const int m0 = blockIdx.x << 7, n0 = blockIdx.y << 7;
  const int l15 = lane & 15, lg = lane >> 4;

  const int r0 = w << 5;
  const int grow = r0 + (lane >> 3);
  const int gcol = (lane & 7) << 3;
  const bf16_t* gA = A + ((size_t)(m0 + grow) << 10) + gcol;
  const bf16_t* gB = Bm + ((size_t)(n0 + grow) << 10) + gcol;
  bf16_t* lA = sA + (r0 << 6);
  bf16_t* lB = sB + (r0 << 6);

  f32x4 acc[4][4] = {};

  for (int k0 = 0; k0 < E_; k0 += 64) {
    __syncthreads();
#pragma unroll
    for (int i = 0; i < 4; ++i) {
      gl_lds16(gA + k0 + ((size_t)(i << 3) << 10), lA + (i << 9));
      gl_lds16(gB + k0 + ((size_t)(i << 3) << 10), lB + (i << 9));
    }
    __syncthreads();
#pragma unroll
    for (int kk = 0; kk < 2; ++kk) {
      bf16x8 af[4], bfr[4];
#pragma unroll
      for (int i = 0; i < 4; ++i)
        af[i] = *(const bf16x8*)(sA + ((wm + (i << 4) + l15) << 6) + (kk << 5) + (lg << 3));
#pragma unroll
      for (int j = 0; j < 4; ++j)
        bfr[j] = *(const bf16x8*)(sB + ((wn + (j << 4) + l15) << 6) + (kk << 5) + (lg << 3));
#pragma unroll
      for (int i = 0; i < 4; ++i)
#pragma unroll
        for (int j = 0; j < 4; ++j)
          acc[i][j] = mfma16(af[i], bfr[j], acc[i][j]);
    }
  }

#pragma unroll
  for (int j = 0; j < 4; ++j) {
    const int n = n0 + wn + (j << 4) + l15;
    const float bn = bias[n];
    const int h = n >> 6, d = n & 63;
#pragma unroll
    for (int i = 0; i < 4; ++i) {
#pragma unroll
      for (int r = 0; r < 4; ++r) {
        const int m = m0 + wm + (i << 4) + (lg << 2) + r;
        const int b = m >> 11, s = m & (S_ - 1);
        out[(((size_t)(b * H_ + h)) * S_ + s) * D_ + d] = (bf16_t)(acc[i][j][r] + bn);
      }
    }
  }
}

// ---------------------------------------------------------------------------
// Kernel 2: fused causal attention, QBLK=128.  grid 512 x 512 threads (8 w).
// Remap: consecutive block ids -> same bh, complementary qt (work-balanced
// CU pairs, shared K/V in L2).  Pass 1: sums-only (K staging, 8 MFMA, exp).
// Pass 2: normalized P once -> plds(bf16); PV; coop full-line stores from
// plds (bf16->f32).  Fill at end.  Each staged K/V tile serves 128 q-rows.
// ---------------------------------------------------------------------------
__global__ __launch_bounds__(512) void attn_kernel(
    const bf16_t* __restrict__ qh, const bf16_t* __restrict__ kh, const bf16_t* __restrict__ vh,
    float* __restrict__ attn, bf16_t* __restrict__ ctx)
{
  constexpr int STR = 72;
  __shared__ __align__(16) bf16_t klds[64 * STR];
  __shared__ __align__(16) bf16_t vrm [64 * 64];     // V row-major [k][d]
  __shared__ __align__(16) bf16_t vt  [64 * STR];    // V^T [d][k]
  __shared__ __align__(16) bf16_t plds[8][16 * STR]; // normalized P [128 rows][64]

  // remap: b -> (qt, bh); pairs {2c,2c+1} share bh with qt sum = 15
  const int b   = blockIdx.x;          // 0..511
  const int s1  = b & 1;
  const int m   = b >> 1;              // 0..255
  const int bh  = m >> 3;              // 0..31
  const int k8  = m & 7;               // 0..7
  const int qt  = s1 ? (15 - k8) : k8; // 0..15
  const int q0  = qt << 7;

  const int t    = threadIdx.x;
  const int lane = t & 63;
  const int w    = t >> 6;             // 0..7
  const int l15  = lane & 15;
  const int lg   = lane >> 4;          // 0..3
  const size_t hbase = (size_t)bh * (size_t)(S_ * D_);

  const int qr_lane = q0 + (w << 4) + l15;
  const bf16_t* qp = qh + hbase + (size_t)qr_lane * D_ + (lg << 3);
  const bf16x8 q_lo = *(const bf16x8*)qp;
  const bf16x8 q_hi = *(const bf16x8*)(qp + 32);

  constexpr float SC = 0.18033688f;    // log2(e)/8

  const int sr  = t >> 3;              // 0..63
  const int sc  = (t & 7) << 3;        // 0..56
  const int td  = t & 63;
  const int tk0 = (t >> 6) << 3;       // 0..56 (one octet per wave)
  const int NT  = (qt << 1) + 2;       // kv tiles covering rows < q0+128

  // ---- pass 1: row exp-sums ----
  float s_sum = 0.f;
  for (int kt = 0; kt < NT; ++kt) {
    __syncthreads();
    *(bf16x8*)(klds + sr * STR + sc) =
        *(const bf16x8*)(kh + hbase + (size_t)((kt << 6) + sr) * D_ + sc);
    __syncthreads();
#pragma unroll
    for (int j = 0; j < 4; ++j) {
      const bf16_t* kp = klds + ((j << 4) + l15) * STR + (lg << 3);
      bf16x8 k_lo = *(const bf16x8*)kp;
      bf16x8 k_hi = *(const bf16x8*)(kp + 32);
      f32x4 sf = { 0.f, 0.f, 0.f, 0.f };
      sf = mfma16(k_lo, q_lo, sf);
      sf = mfma16(k_hi, q_hi, sf);
      const int kc = (kt << 6) + (j << 4) + (lg << 2);
      const int lim = qr_lane - kc;
#pragma unroll
      for (int r = 0; r < 4; ++r)
        s_sum += (r <= lim) ? exp2f(sf[r] * SC) : 0.f;
    }
  }
  float s = s_sum;
  s += __shfl_xor(s, 16);
  s += __shfl_xor(s, 32);
  const float inv_s = 1.f / s;         // own row qr_lane, every lane

  // ---- pass 2: P (once, normalized) -> plds; PV; coop store ----
  f32x4 oacc[4] = {};
  float* attn_bh = attn + (size_t)bh * (size_t)(S_ * S_);
  const int crow = t >> 4;             // 0..31
  const int ccol = (t & 15) << 2;      // 0..60

  for (int kt = 0; kt < NT; ++kt) {
    __syncthreads();   // klds/vrm overwrite safe; prev plds coop-reads done
    {
      const bf16_t* kb = kh + hbase + (size_t)((kt << 6) + sr) * D_ + sc;
      const bf16_t* vb = vh + hbase + (size_t)((kt << 6) + sr) * D_ + sc;
      *(bf16x8*)(klds + sr * STR + sc) = *(const bf16x8*)kb;
      *(bf16x8*)(vrm + (sr << 6) + sc) = *(const bf16x8*)vb;
    }
    __syncthreads();
    // V transpose: one column-octet per thread (8 waves cover all 64 ks)
    {
      bf16x8 col;
#pragma unroll
      for (int e = 0; e < 8; ++e) col[e] = vrm[((tk0 + e) << 6) + td];
      *(bf16x8*)(vt + td * STR + tk0) = col;
    }
    // swapped QK^T -> normalized P -> plds (bf16)
#pragma unroll
    for (int j = 0; j < 4; ++j) {
      const bf16_t* kp = klds + ((j << 4) + l15) * STR + (lg << 3);
      bf16x8 k_lo = *(const bf16x8*)kp;
      bf16x8 k_hi = *(const bf16x8*)(kp + 32);
      f32x4 sf = { 0.f, 0.f, 0.f, 0.f };
      sf = mfma16(k_lo, q_lo, sf);
      sf = mfma16(k_hi, q_hi, sf);
      const int kc = (kt << 6) + (j << 4) + (lg << 2);
      const int lim = qr_lane - kc;
      bf16x4 pb;
#pragma unroll
      for (int r = 0; r < 4; ++r)
        pb[r] = (bf16_t)((r <= lim) ? exp2f(sf[r] * SC) * inv_s : 0.f);
      *(bf16x4*)(&plds[w][l15 * STR + (j << 4) + (lg << 2)]) = pb;
    }
    __syncthreads();   // vt + plds (all waves) ready
    // PV
#pragma unroll
    for (int kk = 0; kk < 2; ++kk) {
      bf16x8 pa = *(const bf16x8*)(&plds[w][l15 * STR + (kk << 5) + (lg << 3)]);
#pragma unroll
      for (int db = 0; db < 4; ++db) {
        bf16x8 vb = *(const bf16x8*)(vt + ((db << 4) + l15) * STR + (kk << 5) + (lg << 3));
        oacc[db] = mfma16(pa, vb, oacc[db]);
      }
    }
    // coop full-line store (128 rows x 256B), bf16 -> f32
#pragma unroll
    for (int rr = 0; rr < 4; ++rr) {
      const int row = (rr << 5) + crow;
      bf16x4 pv4 = *(const bf16x4*)(&plds[row >> 4][(row & 15) * STR + ccol]);
      f32x4 o = { (float)pv4[0], (float)pv4[1], (float)pv4[2], (float)pv4[3] };
      __builtin_nontemporal_store(o,
          (f32x4*)(attn_bh + (size_t)(q0 + row) * S_ + (kt << 6) + ccol));
    }
  }

  // ctx write (P already normalized)
  const int bb = bh >> 4, h = bh & 15;
  const int qr_base = q0 + (w << 4) + (lg << 2);
#pragma unroll
  for (int db = 0; db < 4; ++db) {
    const int d = (db << 4) + l15;
#pragma unroll
    for (int r = 0; r < 4; ++r) {
      const int qr = qr_base + r;
      ctx[((size_t)(bb * S_ + qr)) * E_ + h * D_ + d] = (bf16_t)oacc[db][r];
    }
  }

  // zero-fill tiles beyond the causal band (full-line pattern)
  const f32x4 fz = { 0.f, 0.f, 0.f, 0.f };
  for (int kc0 = NT << 6; kc0 < S_; kc0 += 64) {
#pragma unroll
    for (int rr = 0; rr < 4; ++rr) {
      const int row = (rr << 5) + crow;
      __builtin_nontemporal_store(fz,
          (f32x4*)(attn_bh + (size_t)(q0 + row) * S_ + kc0 + ccol));
    }
  }
}

// ---------------------------------------------------------------------------
// Kernel 3: output projection, m97 structure.
// ---------------------------------------------------------------------------
__global__ __launch_bounds__(256) void out_gemm_kernel(
    bf16_t* __restrict__ wsb, const float* __restrict__ bo, float* __restrict__ out)
{
  __shared__ __align__(16) bf16_t sA[128 * 64];
  __shared__ __align__(16) bf16_t sB[128 * 64];

  const bf16_t* A  = wsb + OFF_CTX;
  const bf16_t* Bm = wsb + OFF_WB + 3u * WSZ;

  const int t = threadIdx.x, lane = t & 63, w = t >> 6;
  const int wm = (w >> 1) << 6, wn = (w & 1) << 6;
  const int m0 = blockIdx.x << 7, n0 = blockIdx.y << 7;
  const int l15 = lane & 15, lg = lane >> 4;

  const int r0 = w << 5;
  const int grow = r0 + (lane >> 3);
  const int gcol = (lane & 7) << 3;
  const bf16_t* gA = A + ((size_t)(m0 + grow) << 10) + gcol;
  const bf16_t* gB = Bm + ((size_t)(n0 + grow) << 10) + gcol;
  bf16_t* lA = sA + (r0 << 6);
  bf16_t* lB = sB + (r0 << 6);

  f32x4 acc[4][4] = {};

  for (int k0 = 0; k0 < E_; k0 += 64) {
    __syncthreads();
#pragma unroll
    for (int i = 0; i < 4; ++i) {
      gl_lds16(gA + k0 + ((size_t)(i << 3) << 10), lA + (i << 9));
      gl_lds16(gB + k0 + ((size_t)(i << 3) << 10), lB + (i << 9));
    }
    __syncthreads();
#pragma unroll
    for (int kk = 0; kk < 2; ++kk) {
      bf16x8 af[4], bfr[4];
#pragma unroll
      for (int i = 0; i < 4; ++i)
        af[i] = *(const bf16x8*)(sA + ((wm + (i << 4) + l15) << 6) + (kk << 5) + (lg << 3));
#pragma unroll
      for (int j = 0; j < 4; ++j)
        bfr[j] = *(const bf16x8*)(sB + ((wn + (j << 4) + l15) << 6) + (kk << 5) + (lg << 3));
#pragma unroll
      for (int i = 0; i < 4; ++i)
#pragma unroll
        for (int j = 0; j < 4; ++j)
          acc[i][j] = mfma16(af[i], bfr[j], acc[i][j]);
    }
  }

#pragma unroll
  for (int j = 0; j < 4; ++j) {
    const int n = n0 + wn + (j << 4) + l15;
    const float bn = bo[n];
#pragma unroll
    for (int i = 0; i < 4; ++i) {
#pragma unroll
      for (int r = 0; r < 4; ++r) {
        const int m = m0 + wm + (i << 4) + (lg << 2) + r;
        out[(size_t)m * E_ + n] = acc[i][j][r] + bn;
      }
    }
  }
}

// ---------------------------------------------------------------------------
extern "C" void kernel_launch(void* const* d_in, const int* in_sizes, int n_in,
                              void* d_out, int out_size, void* d_ws, size_t ws_size,
                              hipStream_t stream) {
  const float* query = (const float*)d_in[0];
  const float* key   = (const float*)d_in[1];
  const float* value = (const float*)d_in[2];
  const float* Wq = (const float*)d_in[4];
  const float* bq = (const float*)d_in[5];
  const float* Wk = (const float*)d_in[6];
  const float* bk = (const float*)d_in[7];
  const float* Wv = (const float*)d_in[8];
  const float* bv = (const float*)d_in[9];
  const float* Wo = (const float*)d_in[10];
  const float* bo = (const float*)d_in[11];

  float* out  = (float*)d_out;                       // [B,S,E]
  float* attn = out + (size_t)B_ * S_ * E_;          // [B,H,S,S]

  bf16_t* wsb = (bf16_t*)d_ws;
  bf16_t* qh  = wsb + OFF_QH;
  bf16_t* kh  = qh + XSZ;
  bf16_t* vh  = kh + XSZ;
  bf16_t* ctx = wsb + OFF_CTX;

  convert_kernel<<<dim3(512, 1, 7), dim3(256), 0, stream>>>(
      query, key, value, Wq, Wk, Wv, Wo, wsb);
  qkv_gemm_kernel<<<dim3(32, 8, 3), dim3(256), 0, stream>>>(wsb, bq, bk, bv);
  attn_kernel<<<dim3(512), dim3(512), 0, stream>>>(qh, kh, vh, attn, ctx);
  out_gemm_kernel<<<dim3(32, 8), dim3(256), 0, stream>>>(wsb, bo, out);
}